// Round 11
// baseline (155.775 us; speedup 1.0000x reference)
//
#include <hip/hip_runtime.h>
#include <math.h>

#define JT 64                // j per block (LDS staged)
#define ITILE 1024           // i per block (4 per thread, 256 threads)
#define T8 8                 // 1024-tiles per dimension
#define NJOB_AB 1024         // 8 i-tiles * 128 j-chunks
#define NJOB_TRI 576         // 36 tri-tiles * 16 chunks
#define NBLK (NJOB_AB + 2 * NJOB_TRI)  // 2176
#define L2E 1.4426950408889634f

typedef float v2f __attribute__((ext_vector_type(2)));

// ---- forced single instructions (compiler scalarizes v2f IR otherwise) ----
__device__ inline float fexp2n(float x) {  // exp2(-x), neg via input modifier
  float r;
  asm("v_exp_f32 %0, -%1" : "=v"(r) : "v"(x));
  return r;
}
__device__ inline float fsqrt(float x) {
  float r;
  asm("v_sqrt_f32 %0, %1" : "=v"(r) : "v"(x));
  return r;
}
__device__ inline v2f pk_add(v2f a, v2f b) {
  v2f d;
  asm("v_pk_add_f32 %0, %1, %2" : "=v"(d) : "v"(a), "v"(b));
  return d;
}
__device__ inline v2f pk_mul(v2f a, v2f b) {
  v2f d;
  asm("v_pk_mul_f32 %0, %1, %2" : "=v"(d) : "v"(a), "v"(b));
  return d;
}
__device__ inline v2f pk_fma(v2f a, v2f b, v2f c) {  // a*b + c
  v2f d;
  asm("v_pk_fma_f32 %0, %1, %2, %3" : "=v"(d) : "v"(a), "v"(b), "v"(c));
  return d;
}

__device__ inline double wred_d(double v) {
#pragma unroll
  for (int o = 32; o > 0; o >>= 1) v += __shfl_down(v, o, 64);
  return v;
}

__device__ inline double bred(double v, double* sm) {
  v = wred_d(v);
  __syncthreads();
  if ((threadIdx.x & 63) == 0) sm[threadIdx.x >> 6] = v;
  __syncthreads();
  return sm[0] + sm[1] + sm[2] + sm[3];
}

// wave 0: reduce 64 prep slots (stride 8, 7 channels) ->
// smean[0..6]=base {Su,Suu,Sux,Suy,Sx,Sy,Sq}, smean[8..14]=target
__device__ inline void slot_reduce(const double* slot, double* smean) {
  if (threadIdx.x < 64) {
    int l = threadIdx.x;
    const double* sl = slot + l * 8;
#pragma unroll
    for (int c = 0; c < 7; ++c) {
      double v = sl[c];
      double vb = (l < 32) ? v : 0.0;
      double vt = (l < 32) ? 0.0 : v;
      vb = wred_d(vb);
      vt = wred_d(vt);
      if (l == 0) {
        smean[c] = vb;
        smean[8 + c] = vt;
      }
    }
  }
}

__global__ __launch_bounds__(256) void prep_kernel(
    const float* __restrict__ base, const float* __restrict__ target,
    const float* __restrict__ log_sigmas, const float* __restrict__ log_scale,
    const float* __restrict__ w1, const float* __restrict__ b1,
    const float* __restrict__ w2, const float* __restrict__ b2,
    float4* __restrict__ pxyu, double* __restrict__ slot,
    unsigned* __restrict__ fctr, int n) {
  __shared__ double sm[4];
  int gid = blockIdx.x * 256 + threadIdx.x;
  int isT = gid >= n;  // uniform per block (n % 256 == 0)
  const float* pts = isT ? target : base;
  int idx = isT ? gid - n : gid;
  float ex = __expf(log_scale[0]);
  float ey = __expf(log_scale[1]);
  float s2 = __expf(log_sigmas[2]);
  float r2 = __fsqrt_rn(L2E / (2.f * s2 * s2));  // coord pre-scale, band 2
  float2 p = ((const float2*)pts)[idx];
  float xr = p.x * ex, yr = p.y * ey;  // MLP input space (no r2!)
  float logit = b2[0];
#pragma unroll
  for (int k = 0; k < 32; ++k) {
    float h = fmaf(xr, w1[k], fmaf(yr, w1[32 + k], b1[k]));
    h = fmaxf(h, 0.f);
    logit = fmaf(h, w2[k], logit);
  }
  float u = fmaxf(logit, 0.f) + log1pf(__expf(-fabsf(logit))) + 1e-6f;
  float X = xr * r2, Y = yr * r2;
  float q = fmaf(X, X, Y * Y);  // |P|^2 (scaled)
  pxyu[gid] = make_float4(X, Y, q, u);
  double su = bred((double)u, sm);
  double qu = bred((double)u * (double)u, sm);
  double mx = bred((double)u * (double)X, sm);
  double my = bred((double)u * (double)Y, sm);
  double sx = bred((double)X, sm);
  double sy = bred((double)Y, sm);
  double sq = bred((double)q, sm);
  if (threadIdx.x == 0) {
    double* s = slot + blockIdx.x * 8;
    s[0] = su;
    s[1] = qu;
    s[2] = mx;
    s[3] = my;
    s[4] = sx;
    s[5] = sy;
    s[6] = sq;
    if (blockIdx.x == 0) *fctr = 0u;
  }
}

// j-parallel packed loop: v2f = 2 consecutive j. i-side broadcasts hoisted.
template <bool AB>
__device__ inline void tile_loop_fast(const float* sx, const float* sy,
                                      const float* su, const float* snb,
                                      const v2f vnxi[4], const v2f vnyi[4],
                                      const v2f vali[4], v2f a0[4], v2f a1[4],
                                      v2f a2[4], float& sdo) {
  float sdl = 0.f, sdh = 0.f;
#pragma unroll 2
  for (int jj = 0; jj < JT / 2; ++jj) {
    v2f vxj = *(const v2f*)&sx[2 * jj];
    v2f vyj = *(const v2f*)&sy[2 * jj];
    v2f vuj = *(const v2f*)&su[2 * jj];
    v2f vnbj;
    if constexpr (AB) vnbj = *(const v2f*)&snb[2 * jj];
#pragma unroll
    for (int i = 0; i < 4; ++i) {
      v2f dx = pk_add(vxj, vnxi[i]);  // xj - xi
      v2f dy = pk_add(vyj, vnyi[i]);
      v2f t = pk_mul(dx, dx);
      v2f pos = pk_fma(dy, dy, t);  // scaled (centered) d2, >= 0
      float k2l = fexp2n(pos.x);
      float k2h = fexp2n(pos.y);
      v2f k2 = {k2l, k2h};
      v2f t2 = pk_mul(k2, k2);
      v2f k1 = pk_mul(t2, t2);  // k2^4  (sigma 1:2)
      v2f t4 = pk_mul(k1, k1);
      v2f k0 = pk_mul(t4, t4);  // k2^16 (sigma 1:4)
      a0[i] = pk_fma(vuj, k0, a0[i]);
      a1[i] = pk_fma(vuj, k1, a1[i]);
      a2[i] = pk_fma(vuj, k2, a2[i]);
      if constexpr (AB) {
        // uncentered scaled d2 = pos + al_i - beta_j; clamp halves
        // (no v_pk_max_f32 on gfx950 -> scalar v_max into scalar v_sqrt)
        v2f d2u = pk_add(pk_add(pos, vali[i]), vnbj);
        sdl += fsqrt(fmaxf(d2u.x, 0.f));
        sdh += fsqrt(fmaxf(d2u.y, 0.f));
      }
    }
  }
  sdo = sdl + sdh;
}

__global__ __launch_bounds__(256) void pair_kernel(
    const float4* __restrict__ pxyu, const double* __restrict__ slot,
    double* __restrict__ paa, double* __restrict__ pbb,
    double* __restrict__ pab, double* __restrict__ psd,
    unsigned* __restrict__ fctr, const float* __restrict__ log_sigmas,
    const float* __restrict__ g_w1, const float* __restrict__ g_b1,
    const float* __restrict__ g_w2, const float* __restrict__ g_b2,
    const float* __restrict__ bias, float* __restrict__ out, int n) {
  __shared__ __align__(16) float sx[JT];
  __shared__ __align__(16) float sy[JT];
  __shared__ __align__(16) float su[JT];
  __shared__ __align__(16) float snb[JT];
  __shared__ double sm[4];
  __shared__ double smean[16];
  __shared__ int lastf;

  int b = blockIdx.x;
  int tid = threadIdx.x;
  int m, it, jt = 0, j0, pidx;
  if (b < NJOB_AB) {  // AB first (heavier), light tri jobs drain last
    m = 2;
    pidx = b;
    it = b >> 7;          // 8 i-tiles
    j0 = (b & 127) * JT;  // 128 j-chunks
  } else {
    int r = b - NJOB_AB;
    m = (r < NJOB_TRI) ? 0 : 1;
    if (m == 1) r -= NJOB_TRI;
    pidx = r;
    int tile = r >> 4;
    int q = r & 15;
    int idx = tile, len = T8;
    it = 0;
    while (idx >= len) {
      idx -= len;
      --len;
      ++it;
    }
    jt = it + idx;
    j0 = jt * ITILE + q * JT;
  }
  const float4* pI = pxyu + ((m == 1) ? n : 0);
  const float4* pJ = pxyu + ((m == 0) ? 0 : n);

  float cx = 0.f, cy = 0.f, cx2 = 0.f, cy2 = 0.f, cc = 0.f;
  if (m == 2) {
    slot_reduce(slot, smean);  // wave 0; consumed after the barrier below
  }

  float s0 = __expf(log_sigmas[0]);
  float s1 = __expf(log_sigmas[1]);
  float s2 = __expf(log_sigmas[2]);
  float rr0 = (s2 * s2) / (s0 * s0);
  float rr1 = (s2 * s2) / (s1 * s1);
  bool fast = (fabsf(rr0 - 16.f) <= 0.016f) && (fabsf(rr1 - 4.f) <= 0.004f);

  if (m == 2) {
    __syncthreads();
    cx = (float)(smean[2] / smean[0] - smean[10] / smean[8]);
    cy = (float)(smean[3] / smean[0] - smean[11] / smean[8]);
    cx2 = 2.f * cx;
    cy2 = 2.f * cy;
    cc = cx * cx + cy * cy;
  }

  if (tid < JT) {
    float4 v = pJ[j0 + tid];
    sx[tid] = v.x;
    sy[tid] = v.y;
    su[tid] = v.w;
    if (m == 2) snb[tid] = -fmaf(cx2, v.x, cy2 * v.y);  // -beta_j
  }
  __syncthreads();

  int i0 = it * ITILE + tid;
  v2f vnxi[4], vnyi[4], vali[4];
  float u[4];
#pragma unroll
  for (int i = 0; i < 4; ++i) {
    float4 P = pI[i0 + i * 256];
    u[i] = P.w;
    float xv = P.x, yv = P.y, alv = 0.f;
    if (m == 2) {  // center i-side; alpha recovers uncentered distance
      xv -= cx;
      yv -= cy;
      alv = fmaf(cx2, xv, cy2 * yv) + cc;
    }
    vnxi[i] = (v2f){-xv, -xv};
    vnyi[i] = (v2f){-yv, -yv};
    vali[i] = (v2f){alv, alv};
  }

  v2f a0[4] = {}, a1[4] = {}, a2[4] = {};
  float sd = 0.f;
  if (fast) {
    if (m == 2)
      tile_loop_fast<true>(sx, sy, su, snb, vnxi, vnyi, vali, a0, a1, a2, sd);
    else
      tile_loop_fast<false>(sx, sy, su, snb, vnxi, vnyi, vali, a0, a1, a2,
                            sd);
  } else {
    // generic sigma-ratio fallback (rare): scalar, correct
    for (int j = 0; j < JT; ++j) {
      float xj = sx[j], yj = sy[j], uj = su[j];
#pragma unroll
      for (int i = 0; i < 4; ++i) {
        float dx = xj + vnxi[i].x;
        float dy = yj + vnyi[i].x;
        float pos = fmaf(dx, dx, dy * dy);
        float k2 = fexp2n(pos);
        float k1 = fexp2n(pos * rr1);
        float k0 = fexp2n(pos * rr0);
        a0[i].x = fmaf(uj, k0, a0[i].x);
        a1[i].x = fmaf(uj, k1, a1[i].x);
        a2[i].x = fmaf(uj, k2, a2[i].x);
        if (m == 2) {
          float d2u = fmaxf(pos + vali[i].x + snb[j], 0.f);
          sd += fsqrt(d2u);
        }
      }
    }
  }

  double wgt = (m != 2 && jt != it) ? 2.0 : 1.0;  // symmetric off-diag tiles
  double c0 = 0.0, c1 = 0.0, c2 = 0.0;
#pragma unroll
  for (int i = 0; i < 4; ++i) {
    c0 += (double)u[i] * (double)(a0[i].x + a0[i].y);
    c1 += (double)u[i] * (double)(a1[i].x + a1[i].y);
    c2 += (double)u[i] * (double)(a2[i].x + a2[i].y);
  }
  double r0 = bred(c0, sm) * wgt;
  double r1 = bred(c1, sm) * wgt;
  double r2d = bred(c2, sm) * wgt;
  double* prow = (m == 0) ? paa : (m == 1) ? pbb : pab;
  int stride = (m == 2) ? NJOB_AB : NJOB_TRI;
  if (tid == 0) {
    prow[0 * stride + pidx] = r0;
    prow[1 * stride + pidx] = r1;
    prow[2 * stride + pidx] = r2d;
  }
  if (m == 2) {
    double rsd = bred((double)sd, sm);
    if (tid == 0) psd[pidx] = rsd;
  }

  // ---- last-block final reduction (ticket + device fence) ----
  if (tid == 0) {
    __threadfence();
    unsigned old = atomicAdd(fctr, 1u);
    lastf = (old == NBLK - 1) ? 1 : 0;
  }
  __syncthreads();
  if (!lastf) return;
  __threadfence();

  slot_reduce(slot, smean);
  __syncthreads();
  int t = tid;
  double vaa[3], vbb[3], vab[3];
  for (int s = 0; s < 3; ++s) {
    const double* pa = paa + s * NJOB_TRI;
    const double* pb = pbb + s * NJOB_TRI;
    const double* pc = pab + s * NJOB_AB;
    double va = pa[t] + pa[t + 256] + ((t < 64) ? pa[t + 512] : 0.0);
    double vb = pb[t] + pb[t + 256] + ((t < 64) ? pb[t + 512] : 0.0);
    double vc = pc[t] + pc[t + 256] + pc[t + 512] + pc[t + 768];
    vaa[s] = bred(va, sm);
    vbb[s] = bred(vb, sm);
    vab[s] = bred(vc, sm);
  }
  double sdt = bred(psd[t] + psd[t + 256] + psd[t + 512] + psd[t + 768], sm);

  if (tid == 0) {
    double Sb = smean[0], Qb = smean[1], St = smean[8], Qt = smean[9];
    double SxB = smean[4], SyB = smean[5], SqB = smean[6];
    double SxT = smean[12], SyT = smean[13], SqT = smean[14];
    double pband[3];
    for (int s = 0; s < 3; ++s)
      pband[s] = vaa[s] / (Sb * Sb) + vbb[s] / (St * St) -
                 2.0 * vab[s] / (Sb * St);
    double s2d = (double)s2;
    double r2sq = (double)L2E / (2.0 * s2d * s2d);
    double NN = (double)n;
    // closed-form Sum d2 (scaled): N*(SqB+SqT) - 2*(SxB*SxT + SyB*SyT)
    double sq_scaled = NN * (SqB + SqT) - 2.0 * (SxB * SxT + SyB * SyT);
    double sd_real = sdt / sqrt(r2sq);
    double sq_real = sq_scaled / r2sq;
    double NM = NN * NN;
    double mean_d = sd_real / NM;
    double var_d = (sq_real - sd_real * sd_real / NM) / (NM - 1.0);
    double wv = (Qb / (Sb * Sb) - 1.0 / NN) / (NN - 1.0) +
                (Qt / (St * St) - 1.0 / NN) / (NN - 1.0);
    float st[4] = {(float)mean_d, (float)var_d, 0.f, (float)wv};
    float gl[3] = {g_b2[0], g_b2[1], g_b2[2]};
    for (int k = 0; k < 32; ++k) {
      float h = g_b1[k];
      for (int c = 0; c < 4; ++c) h = fmaf(st[c], g_w1[c * 32 + k], h);
      h = fmaxf(h, 0.f);
      for (int s = 0; s < 3; ++s) gl[s] = fmaf(h, g_w2[k * 3 + s], gl[s]);
    }
    float gw[3];
    float gsum = 0.f;
    for (int s = 0; s < 3; ++s) {
      gw[s] = fmaxf(gl[s], 0.f) + log1pf(__expf(-fabsf(gl[s])));
      gsum += gw[s];
    }
    double r = 0.0;
    for (int s = 0; s < 3; ++s) r += (double)(gw[s] / gsum) * pband[s];
    out[0] = (float)(r + (double)bias[0]);
  }
}

extern "C" void kernel_launch(void* const* d_in, const int* in_sizes, int n_in,
                              void* d_out, int out_size, void* d_ws,
                              size_t ws_size, hipStream_t stream) {
  const float* base = (const float*)d_in[0];
  const float* target = (const float*)d_in[1];
  const float* log_sigmas = (const float*)d_in[2];
  const float* log_scale = (const float*)d_in[3];
  const float* wn_w1 = (const float*)d_in[4];
  const float* wn_b1 = (const float*)d_in[5];
  const float* wn_w2 = (const float*)d_in[6];
  const float* wn_b2 = (const float*)d_in[7];
  const float* g_w1 = (const float*)d_in[8];
  const float* g_b1 = (const float*)d_in[9];
  const float* g_w2 = (const float*)d_in[10];
  const float* g_b2 = (const float*)d_in[11];
  const float* bias = (const float*)d_in[12];
  int n = in_sizes[0] / 2;  // 8192

  double* dbase = (double*)d_ws;
  double* slot = dbase;                // 64*8 = 512
  double* paa = dbase + 512;           // 3*576
  double* pbb = paa + 3 * NJOB_TRI;    // 3*576
  double* pab = pbb + 3 * NJOB_TRI;    // 3*1024
  double* psd = pab + 3 * NJOB_AB;     // 1024
  double* dend = psd + NJOB_AB;        // 16B-aligned
  float4* pxyu = (float4*)dend;        // 2n
  unsigned* fctr = (unsigned*)(pxyu + 2 * n);

  prep_kernel<<<(2 * n) / 256, 256, 0, stream>>>(
      base, target, log_sigmas, log_scale, wn_w1, wn_b1, wn_w2, wn_b2, pxyu,
      slot, fctr, n);
  pair_kernel<<<NBLK, 256, 0, stream>>>(pxyu, slot, paa, pbb, pab, psd, fctr,
                                        log_sigmas, g_w1, g_b1, g_w2, g_b2,
                                        bias, (float*)d_out, n);
}